// Round 1
// baseline (337.789 us; speedup 1.0000x reference)
//
#include <hip/hip_runtime.h>
#include <type_traits>
#include <utility>

// ---------------- problem constants ----------------
#define B_    8
#define NQ_   1024
#define I_    21760      // 128*128 + 64*64 + 32*32 + 16*16
#define EMB_  256
#define HID_  256
#define H_    8
#define CH_   32

typedef float  f32x4  __attribute__((ext_vector_type(4)));
typedef __bf16 bf16x8 __attribute__((ext_vector_type(8)));
typedef short  s16x8  __attribute__((ext_vector_type(8)));

// ---- MFMA shim: works whether the builtin wants v8bf16 or v8i16 ----
template <typename V, typename = void>
struct bf16_mfma_native : std::false_type {};
template <typename V>
struct bf16_mfma_native<V, std::void_t<decltype(__builtin_amdgcn_mfma_f32_16x16x32_bf16(
    std::declval<V>(), std::declval<V>(), std::declval<f32x4>(), 0, 0, 0))>>
    : std::true_type {};

template <typename V>
__device__ __forceinline__ f32x4 mfma_dispatch(V a, V b, f32x4 c) {
  if constexpr (bf16_mfma_native<V>::value) {
    return __builtin_amdgcn_mfma_f32_16x16x32_bf16(a, b, c, 0, 0, 0);
  } else {
    return __builtin_amdgcn_mfma_f32_16x16x32_bf16(
        __builtin_bit_cast(s16x8, a), __builtin_bit_cast(s16x8, b), c, 0, 0, 0);
  }
}

__device__ __forceinline__ f32x4 MFMA(s16x8 a, s16x8 b, f32x4 c) {
  return mfma_dispatch(__builtin_bit_cast(bf16x8, a), __builtin_bit_cast(bf16x8, b), c);
}

// float -> bf16 bits, round-to-nearest-even
__device__ __forceinline__ unsigned short f2bf(float f) {
  unsigned u = __float_as_uint(f);
  u += 0x7fffu + ((u >> 16) & 1u);
  return (unsigned short)(u >> 16);
}

// ---------------------------------------------------------------
// Generic GEMM, K fixed = 256:  Out[M,N] = A[M,256] @ W[256,N] + bias
// 512 threads = 8 waves. Wave w owns columns {s*128 + w*16 .. +15} for
// s in [0,NS). W strip held in registers (NS*8 bf16x8 frags). A tile of
// 32 rows staged fp32->bf16 in LDS (row stride 264 to dodge bank
// conflicts). 2 MFMAs (row-tiles) x NS strips per K-step, 8 K-steps.
// ---------------------------------------------------------------
template <int NS, bool OUT_BF16>
__global__ __launch_bounds__(512) void gemm_k256(
    const float* __restrict__ A, const float* __restrict__ W,
    const float* __restrict__ bias, void* __restrict__ Out,
    const int N, const int Mtiles) {
  __shared__ __align__(16) short lds[32 * 264];
  const int tid  = threadIdx.x;
  const int lane = tid & 63;
  const int wave = tid >> 6;
  const int quad = lane >> 4;
  const int ln   = lane & 15;

  // --- load W fragments (one-time, strided; L2-resident) ---
  s16x8 bfrag[NS][8];
  float bv[NS];
#pragma unroll
  for (int st = 0; st < NS; ++st) {
    const int ng = st * 128 + wave * 16 + ln;
    bv[st] = bias[ng];
#pragma unroll
    for (int ks = 0; ks < 8; ++ks) {
      s16x8 f;
#pragma unroll
      for (int j = 0; j < 8; ++j)
        f[j] = (short)f2bf(W[(ks * 32 + quad * 8 + j) * N + ng]);
      bfrag[st][ks] = f;
    }
  }

  const int sr = tid >> 4;          // staging row 0..31
  const int sc = (tid & 15) * 16;   // staging col (16 floats per thread)

  for (int t = blockIdx.x; t < Mtiles; t += gridDim.x) {
    const size_t rowBase = (size_t)t * 32;
    // --- stage A tile (32 x 256) fp32 -> bf16 into LDS ---
    {
      const float4* src = (const float4*)(A + (rowBase + sr) * 256 + sc);
      float4 v0 = src[0], v1 = src[1], v2 = src[2], v3 = src[3];
      s16x8 p0, p1;
      p0[0] = (short)f2bf(v0.x); p0[1] = (short)f2bf(v0.y);
      p0[2] = (short)f2bf(v0.z); p0[3] = (short)f2bf(v0.w);
      p0[4] = (short)f2bf(v1.x); p0[5] = (short)f2bf(v1.y);
      p0[6] = (short)f2bf(v1.z); p0[7] = (short)f2bf(v1.w);
      p1[0] = (short)f2bf(v2.x); p1[1] = (short)f2bf(v2.y);
      p1[2] = (short)f2bf(v2.z); p1[3] = (short)f2bf(v2.w);
      p1[4] = (short)f2bf(v3.x); p1[5] = (short)f2bf(v3.y);
      p1[6] = (short)f2bf(v3.z); p1[7] = (short)f2bf(v3.w);
      *(s16x8*)&lds[sr * 264 + sc]     = p0;
      *(s16x8*)&lds[sr * 264 + sc + 8] = p1;
    }
    __syncthreads();

    f32x4 acc[NS][2];
#pragma unroll
    for (int st = 0; st < NS; ++st) {
      acc[st][0] = f32x4{bv[st], bv[st], bv[st], bv[st]};
      acc[st][1] = acc[st][0];
    }
#pragma unroll
    for (int ks = 0; ks < 8; ++ks) {
      s16x8 a0 = *(const s16x8*)&lds[ln * 264 + ks * 32 + quad * 8];
      s16x8 a1 = *(const s16x8*)&lds[(ln + 16) * 264 + ks * 32 + quad * 8];
#pragma unroll
      for (int st = 0; st < NS; ++st) {
        acc[st][0] = MFMA(a0, bfrag[st][ks], acc[st][0]);
        acc[st][1] = MFMA(a1, bfrag[st][ks], acc[st][1]);
      }
    }
    // --- epilogue: D[m = quad*4+reg][n = ln] ---
#pragma unroll
    for (int st = 0; st < NS; ++st) {
      const int ng = st * 128 + wave * 16 + ln;
#pragma unroll
      for (int rt = 0; rt < 2; ++rt) {
#pragma unroll
        for (int r = 0; r < 4; ++r) {
          const size_t m = rowBase + rt * 16 + quad * 4 + r;
          if constexpr (OUT_BF16)
            ((unsigned short*)Out)[m * N + ng] = f2bf(acc[st][rt][r]);
          else
            ((float*)Out)[m * N + ng] = acc[st][rt][r];
        }
      }
    }
    __syncthreads();
  }
}

// ---------------------------------------------------------------
// softmax over L*P=16 logits per (query, head) + sampling points
// thread = (q, h); 65536 threads total
// ---------------------------------------------------------------
__global__ __launch_bounds__(256) void softmax_points_kernel(
    const float* __restrict__ qp, const float* __restrict__ refp,
    float* __restrict__ attn, float* __restrict__ pts) {
  const int gid = blockIdx.x * 256 + threadIdx.x;  // q*8 + h
  const int q = gid >> 3, h = gid & 7;
  const float* base = qp + (size_t)q * 384 + h * 48;

  float s[16];
  float mx = -1e30f;
#pragma unroll
  for (int lp = 0; lp < 16; ++lp) {
    s[lp] = base[lp * 3 + 2];
    mx = fmaxf(mx, s[lp]);
  }
  float sum = 0.f;
#pragma unroll
  for (int lp = 0; lp < 16; ++lp) {
    s[lp] = __expf(s[lp] - mx);
    sum += s[lp];
  }
  const float inv = 1.0f / sum;
  float* ao = attn + (size_t)gid * 16;
#pragma unroll
  for (int lp = 0; lp < 16; ++lp) ao[lp] = s[lp] * inv;

  const float rx = refp[q * 2], ry = refp[q * 2 + 1];
  float* po = pts + (size_t)gid * 32;
  // shapes_f[l] = (H_l, W_l); offsets component i divided by shapes_f[l][i]
  const float invsh[4] = {1.f / 128.f, 1.f / 64.f, 1.f / 32.f, 1.f / 16.f};
#pragma unroll
  for (int l = 0; l < 4; ++l) {
#pragma unroll
    for (int p = 0; p < 4; ++p) {
      const int lp = l * 4 + p;
      po[lp * 2 + 0] = rx + base[lp * 3 + 0] * invsh[l];
      po[lp * 2 + 1] = ry + base[lp * 3 + 1] * invsh[l];
    }
  }
}

// ---------------------------------------------------------------
// MSDA bilinear sampling + attention-weighted sum.
// 1 block (128 thr) per (b,n). Phase1: threads (h,lp) compute 4 folded
// corner weights + gather bases -> LDS. Phase2: threads (h,c2) gather
// bf16 pairs and accumulate. out[b,n, h*32 + 2*c2 + {0,1}]
// ---------------------------------------------------------------
__global__ __launch_bounds__(128) void msda_sample_kernel(
    const unsigned int* __restrict__ imgp,  // bf16 pairs, [B*I][128] uints
    const float* __restrict__ attn, const float* __restrict__ pts,
    float* __restrict__ out) {
  __shared__ __align__(16) float sw[128][4];
  __shared__ __align__(16) int   sib[128][4];
  const int bid = blockIdx.x;        // b*NQ_ + n
  const int b = bid >> 10;
  const int tid = threadIdx.x;

  {
    const int h = tid >> 4, lp = tid & 15, l = lp >> 2;
    const int dims[4]   = {128, 64, 32, 16};
    const int starts[4] = {0, 16384, 20480, 21504};
    const int ww = dims[l], hh = dims[l], start = starts[l];
    const float px = pts[((size_t)bid * 8 + h) * 32 + lp * 2 + 0];
    const float py = pts[((size_t)bid * 8 + h) * 32 + lp * 2 + 1];
    const float a  = attn[((size_t)bid * 8 + h) * 16 + lp];
    const float x = px * (float)ww - 0.5f;
    const float y = py * (float)hh - 0.5f;
    const float x0f = floorf(x), y0f = floorf(y);
    const float wx = x - x0f, wy = y - y0f;
    const int x0 = (int)x0f, y0 = (int)y0f;
    const float cw[4] = {(1.f - wx) * (1.f - wy), wx * (1.f - wy),
                         (1.f - wx) * wy,          wx * wy};
#pragma unroll
    for (int c = 0; c < 4; ++c) {
      const int xi = x0 + (c & 1), yi = y0 + (c >> 1);
      const bool valid = (xi >= 0) & (xi < ww) & (yi >= 0) & (yi < hh);
      const int xc = min(max(xi, 0), ww - 1);
      const int yc = min(max(yi, 0), hh - 1);
      const int idx = start + yc * ww + xc;
      sw[tid][c]  = valid ? a * cw[c] : 0.f;
      sib[tid][c] = ((b * I_ + idx) << 7) + (h << 4);  // uint (bf16-pair) units
    }
  }
  __syncthreads();

  const int h = tid >> 4, c2 = tid & 15;
  float acc0 = 0.f, acc1 = 0.f;
#pragma unroll
  for (int lp = 0; lp < 16; ++lp) {
    const float4 w4 = *(const float4*)sw[h * 16 + lp];
    const int4   i4 = *(const int4*)sib[h * 16 + lp];
    unsigned u;
    u = imgp[i4.x + c2];
    acc0 += w4.x * __uint_as_float(u << 16);
    acc1 += w4.x * __uint_as_float(u & 0xffff0000u);
    u = imgp[i4.y + c2];
    acc0 += w4.y * __uint_as_float(u << 16);
    acc1 += w4.y * __uint_as_float(u & 0xffff0000u);
    u = imgp[i4.z + c2];
    acc0 += w4.z * __uint_as_float(u << 16);
    acc1 += w4.z * __uint_as_float(u & 0xffff0000u);
    u = imgp[i4.w + c2];
    acc0 += w4.w * __uint_as_float(u << 16);
    acc1 += w4.w * __uint_as_float(u & 0xffff0000u);
  }
  float2 r;
  r.x = acc0;
  r.y = acc1;
  *(float2*)&out[(size_t)bid * 256 + h * 32 + c2 * 2] = r;
}

// ---------------------------------------------------------------
// workspace layout (bytes)
// ---------------------------------------------------------------
#define OFF_IMGP 0ULL                        // 174080*256*2  = 89,128,960 (bf16)
#define OFF_QP   89128960ULL                 // 8192*384*4    = 12,582,912
#define OFF_ATTN 101711872ULL                // 8192*128*4    =  4,194,304
#define OFF_PTS  105906176ULL                // 8192*256*4    =  8,388,608
#define OFF_MSDA 114294784ULL                // 8192*256*4    =  8,388,608
#define WS_NEEDED 122683392ULL

extern "C" void kernel_launch(void* const* d_in, const int* in_sizes, int n_in,
                              void* d_out, int out_size, void* d_ws, size_t ws_size,
                              hipStream_t stream) {
  const float* img     = (const float*)d_in[0];
  const float* queries = (const float*)d_in[2];
  const float* refp    = (const float*)d_in[3];
  const float* W_img   = (const float*)d_in[4];
  const float* b_img   = (const float*)d_in[5];
  const float* W_q     = (const float*)d_in[6];
  const float* b_q     = (const float*)d_in[7];
  const float* W_out   = (const float*)d_in[8];
  const float* b_out   = (const float*)d_in[9];

  if (ws_size < WS_NEEDED) return;  // workspace too small -> fail loudly (out stays poisoned)

  char* ws = (char*)d_ws;
  unsigned short* imgp = (unsigned short*)(ws + OFF_IMGP);
  float* qp   = (float*)(ws + OFF_QP);
  float* attn = (float*)(ws + OFF_ATTN);
  float* pts  = (float*)(ws + OFF_PTS);
  float* msda = (float*)(ws + OFF_MSDA);

  // img_p = img @ W_img + b_img   (174080 x 256) -> bf16
  hipLaunchKernelGGL((gemm_k256<2, true>), dim3(512), dim3(512), 0, stream,
                     img, W_img, b_img, (void*)imgp, 256, I_ * B_ / 32);
  // qp = queries @ W_q + b_q      (8192 x 384) -> fp32
  hipLaunchKernelGGL((gemm_k256<3, false>), dim3(256), dim3(512), 0, stream,
                     queries, W_q, b_q, (void*)qp, 384, B_ * NQ_ / 32);
  // softmax + sampling points
  hipLaunchKernelGGL(softmax_points_kernel, dim3(B_ * NQ_ * H_ / 256), dim3(256), 0, stream,
                     qp, refp, attn, pts);
  // bilinear sampling + attention reduce
  hipLaunchKernelGGL(msda_sample_kernel, dim3(B_ * NQ_), dim3(128), 0, stream,
                     (const unsigned int*)imgp, attn, pts, msda);
  // out = msda @ W_out + b_out    (8192 x 256) -> fp32
  hipLaunchKernelGGL((gemm_k256<2, false>), dim3(256), dim3(512), 0, stream,
                     msda, W_out, b_out, d_out, 256, B_ * NQ_ / 32);
}